// Round 1
// baseline (10002.463 us; speedup 1.0000x reference)
//
#include <hip/hip_runtime.h>
#include <math.h>

// ---------------- problem sizes ----------------
#define BATCH   1024
#define NCAND   100000
#define DM      128
#define DB      256
#define NNUM    64
#define CTXS    96
#define ECH     25000       // candidate-encoder M chunk (4 chunks)
#define TROWS   256         // t-net batch rows per chunk (4 chunks)
#define TP      (TROWS*CTXS) // 24576 pairs per t-net chunk

// ---------------- workspace offsets (in floats) ----------------
#define WT_IN       0u
#define WT_E1       8192u
#define WT_E2       40960u
#define WT_K        73728u
#define WT_T1       90112u
#define WT_T2       122880u
#define WT_P1       155648u
#define WT_P2       188416u
#define OFF_CANDK   221184u      // 100000*128
#define OFF_CANDN   13021184u    // 100000
#define OFF_KB      13121184u    // 1024*128
#define OFF_KBN     13252256u    // 1024
#define OFF_XB      13253280u    // 1024*128
#define OFF_X2B     13384352u    // 1024*128
#define OFF_LNB     13515424u    // 1024*128
#define OFF_HB      13646496u    // 1024*256
#define OFF_XPRED   13908640u    // 1024*128
#define OFF_XFIN    14039712u    // 1024*128
#define OFF_PSIM    14170784u    // 1024*8*96
#define OFF_PIDX    14957216u    // 1024*8*96 (int)
#define OFF_PROBS   15743648u    // 1024*96
#define OFF_TIDX    15841952u    // 1024*96 (int)
#define OFF_YG      15940256u    // 1024*96
#define OFF_SX      16038560u    // 25000*128 (enc X; reused as t-net T2 24576*128)
#define OFF_SX2     19238560u    // 25000*128 (enc X2)
#define OFF_SH      22438560u    // 25000*256 (enc H; reused as t-net TH 24576*256)
#define OFF_SLN     28838560u    // 25000*128 (enc LN out; reused as t-net diff 24576*128)

// ---------------- weight transpose prep ----------------
// W[N][K] row-major -> WT[K][N] so GEMM weight staging is coalesced.
__global__ void __launch_bounds__(256) k_transpose(
    const float* __restrict__ w0, const float* __restrict__ w1,
    const float* __restrict__ w2, const float* __restrict__ w3,
    const float* __restrict__ w4, const float* __restrict__ w5,
    const float* __restrict__ w6, const float* __restrict__ w7,
    float* __restrict__ dst)
{
  const float* src[8] = {w0,w1,w2,w3,w4,w5,w6,w7};
  const int nn[8]  = {128,256,128,128,256,128,256,128};
  const int kkv[8] = { 64,128,256,128,128,256,128,256};
  const int off[8] = {0,8192,40960,73728,90112,122880,155648,188416};
  int stride = gridDim.x*blockDim.x;
  int t0 = blockIdx.x*blockDim.x + threadIdx.x;
#pragma unroll
  for (int m = 0; m < 8; ++m) {
    int total = nn[m]*kkv[m];
    for (int i = t0; i < total; i += stride) {
      int k = i / nn[m];
      int n = i - k*nn[m];
      dst[off[m] + i] = src[m][n*kkv[m] + k];
    }
  }
}

// ---------------- generic fp32 GEMM: C[M,N] = f(A[M,K] @ WT[K,N] (+bias) (+resid)) ----------------
// 64-row tile per block, 256 threads, per-thread 4 rows x (N/16) cols.
template<int N, bool RELU, bool RESID, bool NORM>
__global__ void __launch_bounds__(256) k_gemm(
    const float* __restrict__ A, const float* __restrict__ WT,
    const float* __restrict__ bias, const float* __restrict__ resid,
    float* __restrict__ C, float* __restrict__ nrm,
    int M, int K)
{
  constexpr int G = N/64;   // 2 (N=128) or 4 (N=256) column groups of 64
  __shared__ __align__(16) float sA[64*33];
  __shared__ __align__(16) float sW[32*N];
  __shared__ float sNorm[64];
  const int tid = threadIdx.x;
  const int r0 = blockIdx.x*64;
  const int tr = tid >> 4, tc = tid & 15;
  float acc[4][G*4];
#pragma unroll
  for (int i = 0; i < 4; ++i)
#pragma unroll
    for (int j = 0; j < G*4; ++j) acc[i][j] = 0.f;

  for (int kc = 0; kc < K; kc += 32) {
    for (int i = tid; i < 64*32; i += 256) {
      int r = i >> 5, kk = i & 31;
      int gr = r0 + r;
      sA[r*33 + kk] = (gr < M) ? A[(size_t)gr*K + kc + kk] : 0.f;
    }
    for (int i = tid; i < 32*N; i += 256) sW[i] = WT[(size_t)kc*N + i];
    __syncthreads();
    for (int kk = 0; kk < 32; ++kk) {
      float a0 = sA[(tr*4+0)*33+kk];
      float a1 = sA[(tr*4+1)*33+kk];
      float a2 = sA[(tr*4+2)*33+kk];
      float a3 = sA[(tr*4+3)*33+kk];
#pragma unroll
      for (int g = 0; g < G; ++g) {
        float4 w = *(const float4*)&sW[kk*N + g*64 + tc*4];
        acc[0][g*4+0] += a0*w.x; acc[0][g*4+1] += a0*w.y; acc[0][g*4+2] += a0*w.z; acc[0][g*4+3] += a0*w.w;
        acc[1][g*4+0] += a1*w.x; acc[1][g*4+1] += a1*w.y; acc[1][g*4+2] += a1*w.z; acc[1][g*4+3] += a1*w.w;
        acc[2][g*4+0] += a2*w.x; acc[2][g*4+1] += a2*w.y; acc[2][g*4+2] += a2*w.z; acc[2][g*4+3] += a2*w.w;
        acc[3][g*4+0] += a3*w.x; acc[3][g*4+1] += a3*w.y; acc[3][g*4+2] += a3*w.z; acc[3][g*4+3] += a3*w.w;
      }
    }
    __syncthreads();
  }

  float rowsq[4] = {0.f,0.f,0.f,0.f};
#pragma unroll
  for (int i = 0; i < 4; ++i) {
    int r = r0 + tr*4 + i;
    if (r < M) {
#pragma unroll
      for (int g = 0; g < G; ++g) {
        int col = g*64 + tc*4;
        float v0 = acc[i][g*4+0], v1 = acc[i][g*4+1], v2 = acc[i][g*4+2], v3 = acc[i][g*4+3];
        if (bias) { v0 += bias[col+0]; v1 += bias[col+1]; v2 += bias[col+2]; v3 += bias[col+3]; }
        if constexpr (RELU) { v0 = fmaxf(v0,0.f); v1 = fmaxf(v1,0.f); v2 = fmaxf(v2,0.f); v3 = fmaxf(v3,0.f); }
        if constexpr (RESID) {
          float4 rv = *(const float4*)&resid[(size_t)r*N + col];
          v0 += rv.x; v1 += rv.y; v2 += rv.z; v3 += rv.w;
        }
        float4 o4; o4.x = v0; o4.y = v1; o4.z = v2; o4.w = v3;
        *(float4*)&C[(size_t)r*N + col] = o4;
        if constexpr (NORM) rowsq[i] += v0*v0 + v1*v1 + v2*v2 + v3*v3;
      }
    }
  }
  if constexpr (NORM) {
    if (tid < 64) sNorm[tid] = 0.f;
    __syncthreads();
#pragma unroll
    for (int i = 0; i < 4; ++i) atomicAdd(&sNorm[tr*4+i], rowsq[i]);
    __syncthreads();
    if (tid < 64 && r0 + tid < M) nrm[r0 + tid] = sNorm[tid];
  }
}

// ---------------- LayerNorm (wave-per-row) ----------------
__global__ void __launch_bounds__(256) k_ln(
    const float* __restrict__ x, const float* __restrict__ g, const float* __restrict__ b,
    float* __restrict__ o, int M)
{
  const int lane = threadIdx.x & 63, w = threadIdx.x >> 6;
  int rb = blockIdx.x*32 + w*8;
  for (int it = 0; it < 8; ++it) {
    int r = rb + it;
    if (r >= M) return;
    float a = x[(size_t)r*128 + lane];
    float c = x[(size_t)r*128 + 64 + lane];
    float s = a + c;
    for (int o2 = 32; o2; o2 >>= 1) s += __shfl_xor(s, o2);
    float mu = s * (1.f/128.f);
    float da = a - mu, dc = c - mu;
    float v = da*da + dc*dc;
    for (int o2 = 32; o2; o2 >>= 1) v += __shfl_xor(v, o2);
    float rs = rsqrtf(v*(1.f/128.f) + 1e-5f);
    o[(size_t)r*128 + lane]      = da*rs*g[lane]    + b[lane];
    o[(size_t)r*128 + 64 + lane] = dc*rs*g[lane+64] + b[lane+64];
  }
}

// ---------------- sims + streaming top-96 ----------------
// grid: (32 row-tiles of 32 rows) x (8 cand-chunks of 12500). 256 threads.
// Per inner chunk of 128 cands: fp32 dot (K-sliced by 32), per-row LDS min-heaps.
__global__ void __launch_bounds__(256) k_sims_topk(
    const float* __restrict__ kb, const float* __restrict__ kbn,
    const float* __restrict__ candk, const float* __restrict__ candn,
    float* __restrict__ psim, int* __restrict__ pidx)
{
  __shared__ __align__(16) float sKbS[32*36];   // kb k-slice [32 rows][32k]
  __shared__ __align__(16) float sCkS[32*132];  // cand k-slice, transposed [32k][128c]
  __shared__ float sS[32*132];                  // sims tile [32 rows][128c]
  __shared__ float ts[32*97];                   // min-heaps (values)
  __shared__ unsigned short ti[32*97];          // min-heaps (local cand idx)
  __shared__ float sKn[32];
  __shared__ float sCn[128];
  __shared__ int pend[32];
  const int tid = threadIdx.x;
  const int r0 = blockIdx.x * 32;
  const int c0 = blockIdx.y * 12500;
  const int rg = tid >> 5, cg = tid & 31;

  if (tid < 32) { sKn[tid] = kbn[r0 + tid]; pend[tid] = 0; }
  for (int i = tid; i < 32*96; i += 256) {
    int r = i/96, s = i - r*96;
    ts[r*97+s] = -__builtin_inff(); ti[r*97+s] = 0;
  }

  const int NCL = 12500;
  const int NCH = (NCL + 127) >> 7;  // 98
  for (int ch = 0; ch < NCH; ++ch) {
    const int cb = ch << 7;
    const int count = (NCL - cb < 128) ? (NCL - cb) : 128;
    float acc[4][4];
#pragma unroll
    for (int i = 0; i < 4; ++i)
#pragma unroll
      for (int q = 0; q < 4; ++q) acc[i][q] = 0.f;

    for (int ks = 0; ks < 4; ++ks) {
      for (int i = tid; i < 1024; i += 256) {
        int r = i >> 5, kk = i & 31;
        sKbS[r*36 + kk] = kb[(size_t)(r0+r)*128 + ks*32 + kk];
      }
      for (int i = tid; i < 4096; i += 256) {
        int cc = i >> 5, kk = i & 31;
        float v = (cc < count) ? candk[(size_t)(c0+cb+cc)*128 + ks*32 + kk] : 0.f;
        sCkS[kk*132 + cc] = v;
      }
      if (ks == 0 && tid < 128) sCn[tid] = (tid < count) ? candn[c0+cb+tid] : __builtin_inff();
      __syncthreads();
#pragma unroll 4
      for (int kk = 0; kk < 32; kk += 4) {
        float4 a0 = *(const float4*)&sKbS[(rg*4+0)*36 + kk];
        float4 a1 = *(const float4*)&sKbS[(rg*4+1)*36 + kk];
        float4 a2 = *(const float4*)&sKbS[(rg*4+2)*36 + kk];
        float4 a3 = *(const float4*)&sKbS[(rg*4+3)*36 + kk];
        const float* cp0 = &sCkS[(kk+0)*132 + cg];
        const float* cp1 = &sCkS[(kk+1)*132 + cg];
        const float* cp2 = &sCkS[(kk+2)*132 + cg];
        const float* cp3 = &sCkS[(kk+3)*132 + cg];
#pragma unroll
        for (int q = 0; q < 4; ++q) {
          float c0v = cp0[q*32], c1v = cp1[q*32], c2v = cp2[q*32], c3v = cp3[q*32];
          acc[0][q] += a0.x*c0v + a0.y*c1v + a0.z*c2v + a0.w*c3v;
          acc[1][q] += a1.x*c0v + a1.y*c1v + a1.z*c2v + a1.w*c3v;
          acc[2][q] += a2.x*c0v + a2.y*c1v + a2.z*c2v + a2.w*c3v;
          acc[3][q] += a3.x*c0v + a3.y*c1v + a3.z*c2v + a3.w*c3v;
        }
      }
      __syncthreads();
    }
    // sims + pending filter
#pragma unroll
    for (int i = 0; i < 4; ++i) {
      int r = rg*4 + i;
      float kn = sKn[r];
      float rt = ts[r*97];
      bool p = false;
#pragma unroll
      for (int q = 0; q < 4; ++q) {
        int c = cg + q*32;
        float s = 2.f*acc[i][q] - kn - sCn[c];
        sS[r*132 + c] = s;
        p |= (s > rt);
      }
      if (p) pend[r] = 1;
    }
    __syncthreads();
    // per-row heap update (owner = one lane per row)
    if (tid < 32 && pend[tid]) {
      const int r = tid;
      float* hts = &ts[r*97];
      unsigned short* hti = &ti[r*97];
      for (int c = 0; c < count; ++c) {
        float s = sS[r*132 + c];
        if (s > hts[0]) {
          int p2 = 0;
          for (;;) {
            int l = 2*p2 + 1;
            if (l >= 96) break;
            int m = (l+1 < 96 && hts[l+1] < hts[l]) ? l+1 : l;
            if (hts[m] >= s) break;
            hts[p2] = hts[m]; hti[p2] = hti[m]; p2 = m;
          }
          hts[p2] = s; hti[p2] = (unsigned short)(cb + c);
        }
      }
      pend[tid] = 0;
    }
    __syncthreads();
  }
  // write partial lists
  for (int i = tid; i < 32*96; i += 256) {
    int r = i/96, s = i - (i/96)*96;
    psim[((size_t)(r0+r)*8 + blockIdx.y)*96 + s] = ts[r*97+s];
    pidx[((size_t)(r0+r)*8 + blockIdx.y)*96 + s] = c0 + (int)ti[r*97+s];
  }
}

// ---------------- merge 8 partial lists per row, softmax, gather y ----------------
__global__ void __launch_bounds__(256) k_merge_softmax(
    const float* __restrict__ psim, const int* __restrict__ pidx,
    const float* __restrict__ cand_y,
    float* __restrict__ probs, int* __restrict__ tidxg, float* __restrict__ ygath)
{
  __shared__ float ms[768]; __shared__ int mi[768];
  __shared__ float sel_s[96]; __shared__ int sel_i[96];
  __shared__ float wv[4]; __shared__ int wp[4];
  __shared__ float ssum;
  const int b = blockIdx.x, tid = threadIdx.x;
  for (int i = tid; i < 768; i += 256) {
    ms[i] = psim[(size_t)b*768 + i];
    mi[i] = pidx[(size_t)b*768 + i];
  }
  __syncthreads();
  for (int round = 0; round < 96; ++round) {
    float best = -__builtin_inff(); int bp = 0;
    for (int t = tid; t < 768; t += 256) {
      float v = ms[t];
      if (v > best) { best = v; bp = t; }
    }
    for (int o = 32; o; o >>= 1) {
      float ob = __shfl_xor(best, o); int obp = __shfl_xor(bp, o);
      if (ob > best) { best = ob; bp = obp; }
    }
    if ((tid & 63) == 0) { wv[tid>>6] = best; wp[tid>>6] = bp; }
    __syncthreads();
    if (tid == 0) {
      float bb = wv[0]; int pp = wp[0];
      for (int w2 = 1; w2 < 4; ++w2) if (wv[w2] > bb) { bb = wv[w2]; pp = wp[w2]; }
      sel_s[round] = bb; sel_i[round] = mi[pp]; ms[pp] = -__builtin_inff();
    }
    __syncthreads();
  }
  if (tid < 96) ms[tid] = expf(sel_s[tid] - sel_s[0]);  // sel_s[0] is the max
  __syncthreads();
  if (tid == 0) { float s = 0.f; for (int c = 0; c < 96; ++c) s += ms[c]; ssum = s; }
  __syncthreads();
  if (tid < 96) {
    probs[(size_t)b*96 + tid] = ms[tid]/ssum;
    int gi = sel_i[tid];
    tidxg[(size_t)b*96 + tid] = gi;
    ygath[(size_t)b*96 + tid] = cand_y[gi];
  }
}

// ---------------- t-net gather: diff = k_b - cand_k[idx] ----------------
__global__ void __launch_bounds__(256) k_gather_diff(
    const float* __restrict__ kb, const float* __restrict__ candk,
    const int* __restrict__ tidxg, float* __restrict__ diff, int p0)
{
  int f = blockIdx.x*256 + threadIdx.x;   // < TP*128
  int pl = f >> 7, d = f & 127;
  int gp = p0 + pl;
  int bb = gp / 96;
  int idx = tidxg[gp];
  diff[f] = kb[(size_t)bb*128 + d] - candk[(size_t)idx*128 + d];
}

// ---------------- context accumulation + residual add ----------------
__global__ void __launch_bounds__(128) k_ctx(
    const float* __restrict__ probs, const float* __restrict__ ygath,
    const float* __restrict__ t2, const float* __restrict__ x2b,
    const float* __restrict__ w_le, const float* __restrict__ b_le,
    float* __restrict__ xfinal, int b0)
{
  int bb = b0 + blockIdx.x;
  int d = threadIdx.x;
  float wle = w_le[d], ble = b_le[d];
  float acc = 0.f;
  int base = (bb - b0)*96;
  for (int c = 0; c < 96; ++c) {
    float p = probs[(size_t)bb*96 + c];
    float y = ygath[(size_t)bb*96 + c];
    acc += p*(y*wle + ble + t2[(size_t)(base + c)*128 + d]);
  }
  xfinal[(size_t)bb*128 + d] = x2b[(size_t)bb*128 + d] + acc;
}

// ---------------- head: LN -> relu -> [2x128] matvec ----------------
__global__ void __launch_bounds__(256) k_head(
    const float* __restrict__ x, const float* __restrict__ g, const float* __restrict__ b,
    const float* __restrict__ Wh, const float* __restrict__ bh,
    float* __restrict__ out, int M)
{
  const int lane = threadIdx.x & 63, w = threadIdx.x >> 6;
  int rb = blockIdx.x*32 + w*8;
  for (int it = 0; it < 8; ++it) {
    int r = rb + it;
    if (r >= M) return;
    float a = x[(size_t)r*128 + lane];
    float c = x[(size_t)r*128 + 64 + lane];
    float s = a + c;
    for (int o = 32; o; o >>= 1) s += __shfl_xor(s, o);
    float mu = s*(1.f/128.f);
    float da = a - mu, dc = c - mu;
    float v = da*da + dc*dc;
    for (int o = 32; o; o >>= 1) v += __shfl_xor(v, o);
    float rs = rsqrtf(v*(1.f/128.f) + 1e-5f);
    float l0 = fmaxf(da*rs*g[lane]    + b[lane],    0.f);
    float l1 = fmaxf(dc*rs*g[lane+64] + b[lane+64], 0.f);
    float p0 = l0*Wh[lane]     + l1*Wh[64+lane];
    float p1 = l0*Wh[128+lane] + l1*Wh[192+lane];
    for (int o = 32; o; o >>= 1) { p0 += __shfl_xor(p0, o); p1 += __shfl_xor(p1, o); }
    if (lane == 0) { out[r*2 + 0] = p0 + bh[0]; out[r*2 + 1] = p1 + bh[1]; }
  }
}

// ---------------- launcher ----------------
extern "C" void kernel_launch(void* const* d_in, const int* in_sizes, int n_in,
                              void* d_out, int out_size, void* d_ws, size_t ws_size,
                              hipStream_t stream) {
  const float* x_num   = (const float*)d_in[0];
  const float* cand_x  = (const float*)d_in[1];
  const float* cand_y  = (const float*)d_in[2];
  const float* W_in    = (const float*)d_in[3];
  const float* b_in    = (const float*)d_in[4];
  const float* enc_W1  = (const float*)d_in[5];
  const float* enc_b1  = (const float*)d_in[6];
  const float* enc_W2  = (const float*)d_in[7];
  const float* enc_b2  = (const float*)d_in[8];
  const float* mix_g   = (const float*)d_in[9];
  const float* mix_b   = (const float*)d_in[10];
  const float* W_k     = (const float*)d_in[11];
  const float* b_k     = (const float*)d_in[12];
  const float* w_le    = (const float*)d_in[13];
  const float* b_le    = (const float*)d_in[14];
  const float* W_t1    = (const float*)d_in[15];
  const float* b_t1    = (const float*)d_in[16];
  const float* W_t2    = (const float*)d_in[17];
  const float* pred_g  = (const float*)d_in[18];
  const float* pred_b  = (const float*)d_in[19];
  const float* pred_W1 = (const float*)d_in[20];
  const float* pred_b1 = (const float*)d_in[21];
  const float* pred_W2 = (const float*)d_in[22];
  const float* pred_b2 = (const float*)d_in[23];
  const float* head_g  = (const float*)d_in[24];
  const float* head_b  = (const float*)d_in[25];
  const float* W_head  = (const float*)d_in[26];
  const float* b_head  = (const float*)d_in[27];

  float* ws  = (float*)d_ws;
  float* out = (float*)d_out;

  float* wt     = ws;                 // all transposed weights
  float* candk  = ws + OFF_CANDK;
  float* candn  = ws + OFF_CANDN;
  float* kb     = ws + OFF_KB;
  float* kbn    = ws + OFF_KBN;
  float* xb     = ws + OFF_XB;
  float* x2b    = ws + OFF_X2B;
  float* lnb    = ws + OFF_LNB;
  float* hb     = ws + OFF_HB;
  float* xpred  = ws + OFF_XPRED;
  float* xfin   = ws + OFF_XFIN;
  float* psim   = ws + OFF_PSIM;
  int*   pidx   = (int*)(ws + OFF_PIDX);
  float* probs  = ws + OFF_PROBS;
  int*   tidxg  = (int*)(ws + OFF_TIDX);
  float* ygath  = ws + OFF_YG;
  float* sx     = ws + OFF_SX;   // enc X   / t-net T2
  float* sx2    = ws + OFF_SX2;  // enc X2
  float* sh     = ws + OFF_SH;   // enc H   / t-net TH
  float* sln    = ws + OFF_SLN;  // enc LN  / t-net diff

  // 1) transpose all big weights once per call
  k_transpose<<<256, 256, 0, stream>>>(W_in, enc_W1, enc_W2, W_k, W_t1, W_t2, pred_W1, pred_W2, wt);

  // 2) batch encoder
  k_gemm<128,false,false,false><<<16, 256, 0, stream>>>(x_num, wt+WT_IN, b_in,   nullptr, xb,  nullptr, BATCH, 64);
  k_gemm<256,true ,false,false><<<16, 256, 0, stream>>>(xb,    wt+WT_E1, enc_b1, nullptr, hb,  nullptr, BATCH, 128);
  k_gemm<128,false,true ,false><<<16, 256, 0, stream>>>(hb,    wt+WT_E2, enc_b2, xb,      x2b, nullptr, BATCH, 256);
  k_ln<<<(BATCH+31)/32, 256, 0, stream>>>(x2b, mix_g, mix_b, lnb, BATCH);
  k_gemm<128,false,false,true ><<<16, 256, 0, stream>>>(lnb,   wt+WT_K,  b_k,    nullptr, kb,  kbn,     BATCH, 128);

  // 3) candidate encoder, 4 chunks of 25000
  for (int ch = 0; ch < 4; ++ch) {
    const float* a0 = cand_x + (size_t)ch*ECH*64;
    float* ck = candk + (size_t)ch*ECH*128;
    float* cn = candn + (size_t)ch*ECH;
    int grid = (ECH + 63)/64;   // 391
    k_gemm<128,false,false,false><<<grid, 256, 0, stream>>>(a0,  wt+WT_IN, b_in,   nullptr, sx,  nullptr, ECH, 64);
    k_gemm<256,true ,false,false><<<grid, 256, 0, stream>>>(sx,  wt+WT_E1, enc_b1, nullptr, sh,  nullptr, ECH, 128);
    k_gemm<128,false,true ,false><<<grid, 256, 0, stream>>>(sh,  wt+WT_E2, enc_b2, sx,      sx2, nullptr, ECH, 256);
    k_ln<<<(ECH+31)/32, 256, 0, stream>>>(sx2, mix_g, mix_b, sln, ECH);
    k_gemm<128,false,false,true ><<<grid, 256, 0, stream>>>(sln, wt+WT_K,  b_k,    nullptr, ck,  cn,      ECH, 128);
  }

  // 4) sims + streaming top-96 partials (32 row-tiles x 8 cand-chunks)
  k_sims_topk<<<dim3(32, 8), 256, 0, stream>>>(kb, kbn, candk, candn, psim, pidx);

  // 5) exact merge + softmax + gather y
  k_merge_softmax<<<BATCH, 256, 0, stream>>>(psim, pidx, cand_y, probs, tidxg, ygath);

  // 6) t-net, 4 chunks of 256 batch rows (24576 pairs)
  for (int tc = 0; tc < 4; ++tc) {
    int p0 = tc*TP, b0 = tc*TROWS;
    k_gather_diff<<<(TP*128)/256, 256, 0, stream>>>(kb, candk, tidxg, sln, p0);
    k_gemm<256,true ,false,false><<<TP/64, 256, 0, stream>>>(sln, wt+WT_T1, b_t1, nullptr, sh, nullptr, TP, 128);
    k_gemm<128,false,false,false><<<TP/64, 256, 0, stream>>>(sh,  wt+WT_T2, nullptr, nullptr, sx, nullptr, TP, 256);
    k_ctx<<<TROWS, 128, 0, stream>>>(probs, ygath, sx, x2b, w_le, b_le, xfin, b0);
  }

  // 7) predictor block (prenorm) + head
  k_ln<<<(BATCH+31)/32, 256, 0, stream>>>(xfin, pred_g, pred_b, lnb, BATCH);
  k_gemm<256,true ,false,false><<<16, 256, 0, stream>>>(lnb, wt+WT_P1, pred_b1, nullptr, hb,    nullptr, BATCH, 128);
  k_gemm<128,false,true ,false><<<16, 256, 0, stream>>>(hb,  wt+WT_P2, pred_b2, xfin,    xpred, nullptr, BATCH, 256);
  k_head<<<(BATCH+31)/32, 256, 0, stream>>>(xpred, head_g, head_b, W_head, b_head, out, BATCH);
}

// Round 2
// 4320.004 us; speedup vs baseline: 2.3154x; 2.3154x over previous
//
#include <hip/hip_runtime.h>
#include <math.h>

// ---------------- problem sizes ----------------
#define BATCH   1024
#define NCAND   100000
#define DM      128
#define DB      256
#define NNUM    64
#define CTXS    96
#define ECH     25000       // candidate-encoder M chunk (4 chunks)
#define TROWS   256         // t-net batch rows per chunk (4 chunks)
#define TP      (TROWS*CTXS) // 24576 pairs per t-net chunk
#define RCH     128         // sims row chunk (8 chunks)

// ---------------- workspace offsets (in floats) ----------------
#define WT_IN       0u
#define WT_E1       8192u
#define WT_E2       40960u
#define WT_K        73728u
#define WT_T1       90112u
#define WT_T2       122880u
#define WT_P1       155648u
#define WT_P2       188416u
#define OFF_CANDK   221184u      // 100000*128
#define OFF_CANDN   13021184u    // 100000
#define OFF_KB      13121184u    // 1024*128
#define OFF_ROWMM   13252256u    // 1024*2 (uint minmax)
#define OFF_XB      13253280u    // 1024*128
#define OFF_X2B     13384352u    // 1024*128
#define OFF_LNB     13515424u    // 1024*128
#define OFF_HB      13646496u    // 1024*256
#define OFF_XPRED   13908640u    // 1024*128
#define OFF_XFIN    14039712u    // 1024*128
#define OFF_PROBS   15743648u    // 1024*96
#define OFF_TIDX    15841952u    // 1024*96 (int)
#define OFF_YG      15940256u    // 1024*96
#define OFF_SX      16038560u    // enc X (25000*128) / t-net T2 / sims buffer start
#define OFF_SX2     19238560u    // enc X2
#define OFF_SH      22438560u    // enc H / t-net TH
#define OFF_SLN     28838560u    // enc LN / t-net diff

// float <-> order-preserving uint
__device__ __forceinline__ unsigned fenc(float f) {
  unsigned b = __float_as_uint(f);
  return b ^ ((b >> 31) ? 0xFFFFFFFFu : 0x80000000u);
}
__device__ __forceinline__ float fdec(unsigned u) {
  unsigned b = (u >> 31) ? (u ^ 0x80000000u) : ~u;
  return __uint_as_float(b);
}

// ---------------- weight transpose prep ----------------
__global__ void __launch_bounds__(256) k_transpose(
    const float* __restrict__ w0, const float* __restrict__ w1,
    const float* __restrict__ w2, const float* __restrict__ w3,
    const float* __restrict__ w4, const float* __restrict__ w5,
    const float* __restrict__ w6, const float* __restrict__ w7,
    float* __restrict__ dst)
{
  const float* src[8] = {w0,w1,w2,w3,w4,w5,w6,w7};
  const int nn[8]  = {128,256,128,128,256,128,256,128};
  const int kkv[8] = { 64,128,256,128,128,256,128,256};
  const int off[8] = {0,8192,40960,73728,90112,122880,155648,188416};
  int stride = gridDim.x*blockDim.x;
  int t0 = blockIdx.x*blockDim.x + threadIdx.x;
#pragma unroll
  for (int m = 0; m < 8; ++m) {
    int total = nn[m]*kkv[m];
    for (int i = t0; i < total; i += stride) {
      int k = i / nn[m];
      int n = i - k*nn[m];
      dst[off[m] + i] = src[m][n*kkv[m] + k];
    }
  }
}

// ---------------- generic fp32 GEMM ----------------
template<int N, bool RELU, bool RESID, bool NORM>
__global__ void __launch_bounds__(256) k_gemm(
    const float* __restrict__ A, const float* __restrict__ WT,
    const float* __restrict__ bias, const float* __restrict__ resid,
    float* __restrict__ C, float* __restrict__ nrm,
    int M, int K)
{
  constexpr int G = N/64;
  __shared__ __align__(16) float sA[64*33];
  __shared__ __align__(16) float sW[32*N];
  __shared__ float sNorm[64];
  const int tid = threadIdx.x;
  const int r0 = blockIdx.x*64;
  const int tr = tid >> 4, tc = tid & 15;
  float acc[4][G*4];
#pragma unroll
  for (int i = 0; i < 4; ++i)
#pragma unroll
    for (int j = 0; j < G*4; ++j) acc[i][j] = 0.f;

  for (int kc = 0; kc < K; kc += 32) {
    for (int i = tid; i < 64*32; i += 256) {
      int r = i >> 5, kk = i & 31;
      int gr = r0 + r;
      sA[r*33 + kk] = (gr < M) ? A[(size_t)gr*K + kc + kk] : 0.f;
    }
    for (int i = tid; i < 32*N; i += 256) sW[i] = WT[(size_t)kc*N + i];
    __syncthreads();
    for (int kk = 0; kk < 32; ++kk) {
      float a0 = sA[(tr*4+0)*33+kk];
      float a1 = sA[(tr*4+1)*33+kk];
      float a2 = sA[(tr*4+2)*33+kk];
      float a3 = sA[(tr*4+3)*33+kk];
#pragma unroll
      for (int g = 0; g < G; ++g) {
        float4 w = *(const float4*)&sW[kk*N + g*64 + tc*4];
        acc[0][g*4+0] += a0*w.x; acc[0][g*4+1] += a0*w.y; acc[0][g*4+2] += a0*w.z; acc[0][g*4+3] += a0*w.w;
        acc[1][g*4+0] += a1*w.x; acc[1][g*4+1] += a1*w.y; acc[1][g*4+2] += a1*w.z; acc[1][g*4+3] += a1*w.w;
        acc[2][g*4+0] += a2*w.x; acc[2][g*4+1] += a2*w.y; acc[2][g*4+2] += a2*w.z; acc[2][g*4+3] += a2*w.w;
        acc[3][g*4+0] += a3*w.x; acc[3][g*4+1] += a3*w.y; acc[3][g*4+2] += a3*w.z; acc[3][g*4+3] += a3*w.w;
      }
    }
    __syncthreads();
  }

  float rowsq[4] = {0.f,0.f,0.f,0.f};
#pragma unroll
  for (int i = 0; i < 4; ++i) {
    int r = r0 + tr*4 + i;
    if (r < M) {
#pragma unroll
      for (int g = 0; g < G; ++g) {
        int col = g*64 + tc*4;
        float v0 = acc[i][g*4+0], v1 = acc[i][g*4+1], v2 = acc[i][g*4+2], v3 = acc[i][g*4+3];
        if (bias) { v0 += bias[col+0]; v1 += bias[col+1]; v2 += bias[col+2]; v3 += bias[col+3]; }
        if constexpr (RELU) { v0 = fmaxf(v0,0.f); v1 = fmaxf(v1,0.f); v2 = fmaxf(v2,0.f); v3 = fmaxf(v3,0.f); }
        if constexpr (RESID) {
          float4 rv = *(const float4*)&resid[(size_t)r*N + col];
          v0 += rv.x; v1 += rv.y; v2 += rv.z; v3 += rv.w;
        }
        float4 o4; o4.x = v0; o4.y = v1; o4.z = v2; o4.w = v3;
        *(float4*)&C[(size_t)r*N + col] = o4;
        if constexpr (NORM) rowsq[i] += v0*v0 + v1*v1 + v2*v2 + v3*v3;
      }
    }
  }
  if constexpr (NORM) {
    if (tid < 64) sNorm[tid] = 0.f;
    __syncthreads();
#pragma unroll
    for (int i = 0; i < 4; ++i) atomicAdd(&sNorm[tr*4+i], rowsq[i]);
    __syncthreads();
    if (tid < 64 && r0 + tid < M) nrm[r0 + tid] = sNorm[tid];
  }
}

// ---------------- LayerNorm (wave-per-row) ----------------
__global__ void __launch_bounds__(256) k_ln(
    const float* __restrict__ x, const float* __restrict__ g, const float* __restrict__ b,
    float* __restrict__ o, int M)
{
  const int lane = threadIdx.x & 63, w = threadIdx.x >> 6;
  int rb = blockIdx.x*32 + w*8;
  for (int it = 0; it < 8; ++it) {
    int r = rb + it;
    if (r >= M) return;
    float a = x[(size_t)r*128 + lane];
    float c = x[(size_t)r*128 + 64 + lane];
    float s = a + c;
    for (int o2 = 32; o2; o2 >>= 1) s += __shfl_xor(s, o2);
    float mu = s * (1.f/128.f);
    float da = a - mu, dc = c - mu;
    float v = da*da + dc*dc;
    for (int o2 = 32; o2; o2 >>= 1) v += __shfl_xor(v, o2);
    float rs = rsqrtf(v*(1.f/128.f) + 1e-5f);
    o[(size_t)r*128 + lane]      = da*rs*g[lane]    + b[lane];
    o[(size_t)r*128 + 64 + lane] = dc*rs*g[lane+64] + b[lane+64];
  }
}

// ---------------- rowmm init ----------------
__global__ void __launch_bounds__(256) k_init_rowmm(unsigned* __restrict__ rowmm)
{
  int i = blockIdx.x*256 + threadIdx.x;   // 2048 entries
  if (i < 2048) rowmm[i] = (i & 1) ? 0xFFFFFFFFu : 0u;  // [even]=max(init 0), [odd]=min(init ~0)
}

// ---------------- sims GEMM: 128 rows x 128 cols per block ----------------
// sims[r][c] = 2*dot(kbc[r], candk[c]) - candn[c]; fused per-row min/max atomics.
__global__ void __launch_bounds__(256) k_sims_gemm(
    const float* __restrict__ kbc,    // [128][128] chunk of kb
    const float* __restrict__ candk,  // [NCAND][128]
    const float* __restrict__ candn,  // [NCAND]
    float* __restrict__ sims,         // [128][NCAND]
    unsigned* __restrict__ rowmm)     // [128][2]
{
  __shared__ __align__(16) float sAT[32*128];  // [k][r]
  __shared__ __align__(16) float sBT[32*132];  // [k][c] padded
  const int tid = threadIdx.x;
  const int c0 = blockIdx.x * 128;
  const int tr = tid >> 4, tc = tid & 15;
  const int tr8 = tr*8, cb = c0 + tc*8;

  float acc[8][8];
#pragma unroll
  for (int i = 0; i < 8; ++i)
#pragma unroll
    for (int j = 0; j < 8; ++j) acc[i][j] = 0.f;

  for (int ks = 0; ks < 128; ks += 32) {
    // stage A slice transposed: conflict-free LDS writes (consecutive lanes -> consecutive r)
    for (int i = tid; i < 1024; i += 256) {
      int r = i & 127, k4 = i >> 7;          // k4 in 0..7
      float4 a = *(const float4*)&kbc[(size_t)r*128 + ks + k4*4];
      sAT[(k4*4+0)*128 + r] = a.x;
      sAT[(k4*4+1)*128 + r] = a.y;
      sAT[(k4*4+2)*128 + r] = a.z;
      sAT[(k4*4+3)*128 + r] = a.w;
    }
    // stage B slice transposed: coalesced global reads (8 lanes cover 128B per c-row)
    for (int i = tid; i < 1024; i += 256) {
      int c = i >> 3, k4 = i & 7;
      int gc = c0 + c;
      float4 bv;
      if (gc < NCAND) bv = *(const float4*)&candk[(size_t)gc*128 + ks + k4*4];
      else { bv.x = bv.y = bv.z = bv.w = 0.f; }
      sBT[(k4*4+0)*132 + c] = bv.x;
      sBT[(k4*4+1)*132 + c] = bv.y;
      sBT[(k4*4+2)*132 + c] = bv.z;
      sBT[(k4*4+3)*132 + c] = bv.w;
    }
    __syncthreads();
    for (int k = 0; k < 32; ++k) {
      float a[8], bb[8];
      *(float4*)&a[0]  = *(const float4*)&sAT[k*128 + tr8];
      *(float4*)&a[4]  = *(const float4*)&sAT[k*128 + tr8 + 4];
      *(float4*)&bb[0] = *(const float4*)&sBT[k*132 + tc*8];
      *(float4*)&bb[4] = *(const float4*)&sBT[k*132 + tc*8 + 4];
#pragma unroll
      for (int i = 0; i < 8; ++i)
#pragma unroll
        for (int j = 0; j < 8; ++j) acc[i][j] += a[i]*bb[j];
    }
    __syncthreads();
  }

  // epilogue: sims = 2*acc - cn; fused per-row minmax
  const bool valid = (cb < NCAND);   // NCAND % 8 == 0: 8-col group all-or-nothing
  float cn[8];
  if (valid) {
    *(float4*)&cn[0] = *(const float4*)&candn[cb];
    *(float4*)&cn[4] = *(const float4*)&candn[cb+4];
  }
#pragma unroll
  for (int i = 0; i < 8; ++i) {
    int r = tr8 + i;
    float vmax = -__builtin_inff(), vmin = __builtin_inff();
    float srow[8];
    if (valid) {
#pragma unroll
      for (int q = 0; q < 8; ++q) {
        float s = 2.f*acc[i][q] - cn[q];
        srow[q] = s;
        vmax = fmaxf(vmax, s); vmin = fminf(vmin, s);
      }
      float* dst = &sims[(size_t)r*NCAND + cb];
      *(float4*)&dst[0] = *(float4*)&srow[0];
      *(float4*)&dst[4] = *(float4*)&srow[4];
    }
#pragma unroll
    for (int m = 1; m < 16; m <<= 1) {
      vmax = fmaxf(vmax, __shfl_xor(vmax, m));
      vmin = fminf(vmin, __shfl_xor(vmin, m));
    }
    if ((tid & 15) == 0) {
      atomicMax(&rowmm[r*2+0], fenc(vmax));
      atomicMin(&rowmm[r*2+1], fenc(vmin));
    }
  }
}

// ---------------- top-96 select + softmax + gathers (one block per row) ----------------
__global__ void __launch_bounds__(256) k_select(
    const float* __restrict__ sims, const unsigned* __restrict__ rowmm,
    const float* __restrict__ cand_y,
    float* __restrict__ probs, int* __restrict__ tidxg, float* __restrict__ ygath,
    int r0)
{
  __shared__ unsigned hist[2048];
  __shared__ unsigned wsum[256];
  __shared__ float tv[3072];
  __shared__ int   tix[3072];
  __shared__ float selv[96];
  __shared__ int   seli[96];
  __shared__ unsigned scnt[2];
  __shared__ int sb_s; __shared__ int above_s;
  __shared__ float s_lo, s_inv;
  __shared__ float wv[4]; __shared__ int wp[4];
  __shared__ float smax_s, ssum_s;

  const int tid = threadIdx.x;
  const int row = blockIdx.x;
  const float4* S4 = (const float4*)(sims + (size_t)row*NCAND);

  if (tid == 0) {
    float hi = fdec(rowmm[row*2+0]);
    float lo = fdec(rowmm[row*2+1]);
    float rng = hi - lo;
    s_lo = lo;
    s_inv = (rng > 0.f) ? (2048.f / rng) : 0.f;
    scnt[0] = 0; scnt[1] = 0;
  }
  for (int i = tid; i < 2048; i += 256) hist[i] = 0;
  __syncthreads();
  const float lo = s_lo, inv = s_inv;

  // pass 1: histogram
  for (int i = tid; i < NCAND/4; i += 256) {
    float4 v = S4[i];
    int b0 = min(max((int)((v.x-lo)*inv), 0), 2047);
    int b1 = min(max((int)((v.y-lo)*inv), 0), 2047);
    int b2 = min(max((int)((v.z-lo)*inv), 0), 2047);
    int b3 = min(max((int)((v.w-lo)*inv), 0), 2047);
    atomicAdd(&hist[b0], 1u); atomicAdd(&hist[b1], 1u);
    atomicAdd(&hist[b2], 1u); atomicAdd(&hist[b3], 1u);
  }
  __syncthreads();
  { unsigned s = 0;
#pragma unroll
    for (int j = 0; j < 8; ++j) s += hist[tid*8 + j];
    wsum[tid] = s; }
  __syncthreads();
  if (tid == 0) {
    unsigned cum = 0; int g = 255;
    while (cum + wsum[g] < 96u) { cum += wsum[g]; --g; }
    int b = g*8 + 7;
    while (cum + hist[b] < 96u) { cum += hist[b]; --b; }
    sb_s = b; above_s = (int)cum;
  }
  __syncthreads();
  const int sb = sb_s, above = above_s;

  // pass 2: emission
  for (int i = tid; i < NCAND/4; i += 256) {
    float4 v = S4[i];
    float xs[4] = {v.x, v.y, v.z, v.w};
#pragma unroll
    for (int j = 0; j < 4; ++j) {
      float x = xs[j];
      int b = min(max((int)((x-lo)*inv), 0), 2047);
      if (b > sb) {
        unsigned p = atomicAdd(&scnt[0], 1u);
        selv[p] = x; seli[p] = i*4 + j;
      } else if (b == sb) {
        unsigned p = atomicAdd(&scnt[1], 1u);
        if (p < 3072u) { tv[p] = x; tix[p] = i*4 + j; }
      }
    }
  }
  __syncthreads();
  const int need = 96 - above;
  const int tcnt = min((int)scnt[1], 3072);
  for (int rd = 0; rd < need; ++rd) {
    float best = -__builtin_inff(); int bp = -1;
    for (int t = tid; t < tcnt; t += 256) {
      float v = tv[t];
      if (v > best) { best = v; bp = t; }
    }
    for (int o = 32; o; o >>= 1) {
      float ob = __shfl_xor(best, o); int obp = __shfl_xor(bp, o);
      if (ob > best) { best = ob; bp = obp; }
    }
    if ((tid & 63) == 0) { wv[tid>>6] = best; wp[tid>>6] = bp; }
    __syncthreads();
    if (tid == 0) {
      float bb = wv[0]; int pp = wp[0];
      for (int w2 = 1; w2 < 4; ++w2) if (wv[w2] > bb) { bb = wv[w2]; pp = wp[w2]; }
      selv[above + rd] = bb; seli[above + rd] = tix[pp]; tv[pp] = -__builtin_inff();
    }
    __syncthreads();
  }

  // softmax + gather
  if (tid == 0) {
    float m = selv[0];
    for (int i = 1; i < 96; ++i) m = fmaxf(m, selv[i]);
    smax_s = m;
  }
  __syncthreads();
  if (tid < 96) selv[tid] = expf(selv[tid] - smax_s);
  __syncthreads();
  if (tid == 0) {
    float s = 0.f;
    for (int i = 0; i < 96; ++i) s += selv[i];
    ssum_s = s;
  }
  __syncthreads();
  if (tid < 96) {
    int gr = r0 + row;
    int gi = seli[tid];
    probs[(size_t)gr*96 + tid] = selv[tid]/ssum_s;
    tidxg[(size_t)gr*96 + tid] = gi;
    ygath[(size_t)gr*96 + tid] = cand_y[gi];
  }
}

// ---------------- t-net gather: diff = k_b - cand_k[idx] ----------------
__global__ void __launch_bounds__(256) k_gather_diff(
    const float* __restrict__ kb, const float* __restrict__ candk,
    const int* __restrict__ tidxg, float* __restrict__ diff, int p0)
{
  int f = blockIdx.x*256 + threadIdx.x;
  int pl = f >> 7, d = f & 127;
  int gp = p0 + pl;
  int bb = gp / 96;
  int idx = tidxg[gp];
  diff[f] = kb[(size_t)bb*128 + d] - candk[(size_t)idx*128 + d];
}

// ---------------- context accumulation + residual add ----------------
__global__ void __launch_bounds__(128) k_ctx(
    const float* __restrict__ probs, const float* __restrict__ ygath,
    const float* __restrict__ t2, const float* __restrict__ x2b,
    const float* __restrict__ w_le, const float* __restrict__ b_le,
    float* __restrict__ xfinal, int b0)
{
  int bb = b0 + blockIdx.x;
  int d = threadIdx.x;
  float wle = w_le[d], ble = b_le[d];
  float acc = 0.f;
  int base = (bb - b0)*96;
  for (int c = 0; c < 96; ++c) {
    float p = probs[(size_t)bb*96 + c];
    float y = ygath[(size_t)bb*96 + c];
    acc += p*(y*wle + ble + t2[(size_t)(base + c)*128 + d]);
  }
  xfinal[(size_t)bb*128 + d] = x2b[(size_t)bb*128 + d] + acc;
}

// ---------------- head ----------------
__global__ void __launch_bounds__(256) k_head(
    const float* __restrict__ x, const float* __restrict__ g, const float* __restrict__ b,
    const float* __restrict__ Wh, const float* __restrict__ bh,
    float* __restrict__ out, int M)
{
  const int lane = threadIdx.x & 63, w = threadIdx.x >> 6;
  int rb = blockIdx.x*32 + w*8;
  for (int it = 0; it < 8; ++it) {
    int r = rb + it;
    if (r >= M) return;
    float a = x[(size_t)r*128 + lane];
    float c = x[(size_t)r*128 + 64 + lane];
    float s = a + c;
    for (int o = 32; o; o >>= 1) s += __shfl_xor(s, o);
    float mu = s*(1.f/128.f);
    float da = a - mu, dc = c - mu;
    float v = da*da + dc*dc;
    for (int o = 32; o; o >>= 1) v += __shfl_xor(v, o);
    float rs = rsqrtf(v*(1.f/128.f) + 1e-5f);
    float l0 = fmaxf(da*rs*g[lane]    + b[lane],    0.f);
    float l1 = fmaxf(dc*rs*g[lane+64] + b[lane+64], 0.f);
    float p0 = l0*Wh[lane]     + l1*Wh[64+lane];
    float p1 = l0*Wh[128+lane] + l1*Wh[192+lane];
    for (int o = 32; o; o >>= 1) { p0 += __shfl_xor(p0, o); p1 += __shfl_xor(p1, o); }
    if (lane == 0) { out[r*2 + 0] = p0 + bh[0]; out[r*2 + 1] = p1 + bh[1]; }
  }
}

// ---------------- launcher ----------------
extern "C" void kernel_launch(void* const* d_in, const int* in_sizes, int n_in,
                              void* d_out, int out_size, void* d_ws, size_t ws_size,
                              hipStream_t stream) {
  const float* x_num   = (const float*)d_in[0];
  const float* cand_x  = (const float*)d_in[1];
  const float* cand_y  = (const float*)d_in[2];
  const float* W_in    = (const float*)d_in[3];
  const float* b_in    = (const float*)d_in[4];
  const float* enc_W1  = (const float*)d_in[5];
  const float* enc_b1  = (const float*)d_in[6];
  const float* enc_W2  = (const float*)d_in[7];
  const float* enc_b2  = (const float*)d_in[8];
  const float* mix_g   = (const float*)d_in[9];
  const float* mix_b   = (const float*)d_in[10];
  const float* W_k     = (const float*)d_in[11];
  const float* b_k     = (const float*)d_in[12];
  const float* w_le    = (const float*)d_in[13];
  const float* b_le    = (const float*)d_in[14];
  const float* W_t1    = (const float*)d_in[15];
  const float* b_t1    = (const float*)d_in[16];
  const float* W_t2    = (const float*)d_in[17];
  const float* pred_g  = (const float*)d_in[18];
  const float* pred_b  = (const float*)d_in[19];
  const float* pred_W1 = (const float*)d_in[20];
  const float* pred_b1 = (const float*)d_in[21];
  const float* pred_W2 = (const float*)d_in[22];
  const float* pred_b2 = (const float*)d_in[23];
  const float* head_g  = (const float*)d_in[24];
  const float* head_b  = (const float*)d_in[25];
  const float* W_head  = (const float*)d_in[26];
  const float* b_head  = (const float*)d_in[27];

  float* ws  = (float*)d_ws;
  float* out = (float*)d_out;

  float*    wt     = ws;
  float*    candk  = ws + OFF_CANDK;
  float*    candn  = ws + OFF_CANDN;
  float*    kb     = ws + OFF_KB;
  unsigned* rowmm  = (unsigned*)(ws + OFF_ROWMM);
  float*    xb     = ws + OFF_XB;
  float*    x2b    = ws + OFF_X2B;
  float*    lnb    = ws + OFF_LNB;
  float*    hb     = ws + OFF_HB;
  float*    xpred  = ws + OFF_XPRED;
  float*    xfin   = ws + OFF_XFIN;
  float*    probs  = ws + OFF_PROBS;
  int*      tidxg  = (int*)(ws + OFF_TIDX);
  float*    ygath  = ws + OFF_YG;
  float*    sx     = ws + OFF_SX;
  float*    sx2    = ws + OFF_SX2;
  float*    sh     = ws + OFF_SH;
  float*    sln    = ws + OFF_SLN;
  float*    simsbuf = ws + OFF_SX;   // 128*100000 floats, overlaps dead enc scratch

  // 1) weight transposes
  k_transpose<<<256, 256, 0, stream>>>(W_in, enc_W1, enc_W2, W_k, W_t1, W_t2, pred_W1, pred_W2, wt);

  // 2) batch encoder
  k_gemm<128,false,false,false><<<16, 256, 0, stream>>>(x_num, wt+WT_IN, b_in,   nullptr, xb,  nullptr, BATCH, 64);
  k_gemm<256,true ,false,false><<<16, 256, 0, stream>>>(xb,    wt+WT_E1, enc_b1, nullptr, hb,  nullptr, BATCH, 128);
  k_gemm<128,false,true ,false><<<16, 256, 0, stream>>>(hb,    wt+WT_E2, enc_b2, xb,      x2b, nullptr, BATCH, 256);
  k_ln<<<(BATCH+31)/32, 256, 0, stream>>>(x2b, mix_g, mix_b, lnb, BATCH);
  k_gemm<128,false,false,false><<<16, 256, 0, stream>>>(lnb,   wt+WT_K,  b_k,    nullptr, kb,  nullptr, BATCH, 128);

  // 3) candidate encoder, 4 chunks of 25000
  for (int ch = 0; ch < 4; ++ch) {
    const float* a0 = cand_x + (size_t)ch*ECH*64;
    float* ck = candk + (size_t)ch*ECH*128;
    float* cn = candn + (size_t)ch*ECH;
    int grid = (ECH + 63)/64;
    k_gemm<128,false,false,false><<<grid, 256, 0, stream>>>(a0,  wt+WT_IN, b_in,   nullptr, sx,  nullptr, ECH, 64);
    k_gemm<256,true ,false,false><<<grid, 256, 0, stream>>>(sx,  wt+WT_E1, enc_b1, nullptr, sh,  nullptr, ECH, 128);
    k_gemm<128,false,true ,false><<<grid, 256, 0, stream>>>(sh,  wt+WT_E2, enc_b2, sx,      sx2, nullptr, ECH, 256);
    k_ln<<<(ECH+31)/32, 256, 0, stream>>>(sx2, mix_g, mix_b, sln, ECH);
    k_gemm<128,false,false,true ><<<grid, 256, 0, stream>>>(sln, wt+WT_K,  b_k,    nullptr, ck,  cn,      ECH, 128);
  }

  // 4) sims + exact top-96, 8 row chunks of 128
  k_init_rowmm<<<8, 256, 0, stream>>>(rowmm);
  for (int ch = 0; ch < 8; ++ch) {
    k_sims_gemm<<<(NCAND+127)/128, 256, 0, stream>>>(
        kb + (size_t)ch*RCH*128, candk, candn, simsbuf, rowmm + ch*RCH*2);
    k_select<<<RCH, 256, 0, stream>>>(
        simsbuf, rowmm + ch*RCH*2, cand_y, probs, tidxg, ygath, ch*RCH);
  }

  // 5) t-net, 4 chunks of 256 batch rows
  for (int tc = 0; tc < 4; ++tc) {
    int p0 = tc*TP, b0 = tc*TROWS;
    k_gather_diff<<<(TP*128)/256, 256, 0, stream>>>(kb, candk, tidxg, sln, p0);
    k_gemm<256,true ,false,false><<<TP/64, 256, 0, stream>>>(sln, wt+WT_T1, b_t1, nullptr, sh, nullptr, TP, 128);
    k_gemm<128,false,false,false><<<TP/64, 256, 0, stream>>>(sh,  wt+WT_T2, nullptr, nullptr, sx, nullptr, TP, 256);
    k_ctx<<<TROWS, 128, 0, stream>>>(probs, ygath, sx, x2b, w_le, b_le, xfin, b0);
  }

  // 6) predictor block + head
  k_ln<<<(BATCH+31)/32, 256, 0, stream>>>(xfin, pred_g, pred_b, lnb, BATCH);
  k_gemm<256,true ,false,false><<<16, 256, 0, stream>>>(lnb, wt+WT_P1, pred_b1, nullptr, hb,    nullptr, BATCH, 128);
  k_gemm<128,false,true ,false><<<16, 256, 0, stream>>>(hb,  wt+WT_P2, pred_b2, xfin,    xpred, nullptr, BATCH, 256);
  k_head<<<(BATCH+31)/32, 256, 0, stream>>>(xpred, head_g, head_b, W_head, b_head, out, BATCH);
}

// Round 3
// 3663.679 us; speedup vs baseline: 2.7302x; 1.1791x over previous
//
#include <hip/hip_runtime.h>
#include <math.h>

// ---------------- problem sizes ----------------
#define BATCH   1024
#define NCAND   100000
#define DM      128
#define DB      256
#define NNUM    64
#define CTXS    96
#define ECH     25000       // candidate-encoder M chunk (4 chunks)
#define TROWS   256         // t-net batch rows per chunk (4 chunks)
#define TP      (TROWS*CTXS) // 24576 pairs per t-net chunk
#define RCH     128         // sims row chunk (8 chunks)

// ---------------- workspace offsets (in floats) ----------------
#define WT_IN       0u
#define WT_E1       8192u
#define WT_E2       40960u
#define WT_K        73728u
#define WT_T1       90112u
#define WT_T2       122880u
#define WT_P1       155648u
#define WT_P2       188416u
#define OFF_CANDK   221184u      // 100000*128
#define OFF_CANDN   13021184u    // 100000
#define OFF_KB      13121184u    // 1024*128
#define OFF_ROWMM   13252256u    // 1024*2 (uint minmax)
#define OFF_XB      13253280u    // 1024*128
#define OFF_X2B     13384352u    // 1024*128
#define OFF_LNB     13515424u    // 1024*128
#define OFF_HB      13646496u    // 1024*256
#define OFF_XPRED   13908640u    // 1024*128
#define OFF_XFIN    14039712u    // 1024*128
#define OFF_PROBS   15743648u    // 1024*96
#define OFF_TIDX    15841952u    // 1024*96 (int)
#define OFF_YG      15940256u    // 1024*96
#define OFF_SX      16038560u    // enc X (25000*128) / t-net T2 / sims buffer start
#define OFF_SX2     19238560u    // enc X2
#define OFF_SH      22438560u    // enc H / t-net TH
#define OFF_SLN     28838560u    // enc LN / t-net diff

// float <-> order-preserving uint
__device__ __forceinline__ unsigned fenc(float f) {
  unsigned b = __float_as_uint(f);
  return b ^ ((b >> 31) ? 0xFFFFFFFFu : 0x80000000u);
}
__device__ __forceinline__ float fdec(unsigned u) {
  unsigned b = (u >> 31) ? (u ^ 0x80000000u) : ~u;
  return __uint_as_float(b);
}

// ---------------- weight transpose prep ----------------
__global__ void __launch_bounds__(256) k_transpose(
    const float* __restrict__ w0, const float* __restrict__ w1,
    const float* __restrict__ w2, const float* __restrict__ w3,
    const float* __restrict__ w4, const float* __restrict__ w5,
    const float* __restrict__ w6, const float* __restrict__ w7,
    float* __restrict__ dst)
{
  const float* src[8] = {w0,w1,w2,w3,w4,w5,w6,w7};
  const int nn[8]  = {128,256,128,128,256,128,256,128};
  const int kkv[8] = { 64,128,256,128,128,256,128,256};
  const int off[8] = {0,8192,40960,73728,90112,122880,155648,188416};
  int stride = gridDim.x*blockDim.x;
  int t0 = blockIdx.x*blockDim.x + threadIdx.x;
#pragma unroll
  for (int m = 0; m < 8; ++m) {
    int total = nn[m]*kkv[m];
    for (int i = t0; i < total; i += stride) {
      int k = i / nn[m];
      int n = i - k*nn[m];
      dst[off[m] + i] = src[m][n*kkv[m] + k];
    }
  }
}

// ---------------- generic fp32 GEMM ----------------
template<int N, bool RELU, bool RESID, bool NORM>
__global__ void __launch_bounds__(256) k_gemm(
    const float* __restrict__ A, const float* __restrict__ WT,
    const float* __restrict__ bias, const float* __restrict__ resid,
    float* __restrict__ C, float* __restrict__ nrm,
    int M, int K)
{
  constexpr int G = N/64;
  __shared__ __align__(16) float sA[64*33];
  __shared__ __align__(16) float sW[32*N];
  __shared__ float sNorm[64];
  const int tid = threadIdx.x;
  const int r0 = blockIdx.x*64;
  const int tr = tid >> 4, tc = tid & 15;
  float acc[4][G*4];
#pragma unroll
  for (int i = 0; i < 4; ++i)
#pragma unroll
    for (int j = 0; j < G*4; ++j) acc[i][j] = 0.f;

  for (int kc = 0; kc < K; kc += 32) {
    for (int i = tid; i < 64*32; i += 256) {
      int r = i >> 5, kk = i & 31;
      int gr = r0 + r;
      sA[r*33 + kk] = (gr < M) ? A[(size_t)gr*K + kc + kk] : 0.f;
    }
    for (int i = tid; i < 32*N; i += 256) sW[i] = WT[(size_t)kc*N + i];
    __syncthreads();
    for (int kk = 0; kk < 32; ++kk) {
      float a0 = sA[(tr*4+0)*33+kk];
      float a1 = sA[(tr*4+1)*33+kk];
      float a2 = sA[(tr*4+2)*33+kk];
      float a3 = sA[(tr*4+3)*33+kk];
#pragma unroll
      for (int g = 0; g < G; ++g) {
        float4 w = *(const float4*)&sW[kk*N + g*64 + tc*4];
        acc[0][g*4+0] += a0*w.x; acc[0][g*4+1] += a0*w.y; acc[0][g*4+2] += a0*w.z; acc[0][g*4+3] += a0*w.w;
        acc[1][g*4+0] += a1*w.x; acc[1][g*4+1] += a1*w.y; acc[1][g*4+2] += a1*w.z; acc[1][g*4+3] += a1*w.w;
        acc[2][g*4+0] += a2*w.x; acc[2][g*4+1] += a2*w.y; acc[2][g*4+2] += a2*w.z; acc[2][g*4+3] += a2*w.w;
        acc[3][g*4+0] += a3*w.x; acc[3][g*4+1] += a3*w.y; acc[3][g*4+2] += a3*w.z; acc[3][g*4+3] += a3*w.w;
      }
    }
    __syncthreads();
  }

  float rowsq[4] = {0.f,0.f,0.f,0.f};
#pragma unroll
  for (int i = 0; i < 4; ++i) {
    int r = r0 + tr*4 + i;
    if (r < M) {
#pragma unroll
      for (int g = 0; g < G; ++g) {
        int col = g*64 + tc*4;
        float v0 = acc[i][g*4+0], v1 = acc[i][g*4+1], v2 = acc[i][g*4+2], v3 = acc[i][g*4+3];
        if (bias) { v0 += bias[col+0]; v1 += bias[col+1]; v2 += bias[col+2]; v3 += bias[col+3]; }
        if constexpr (RELU) { v0 = fmaxf(v0,0.f); v1 = fmaxf(v1,0.f); v2 = fmaxf(v2,0.f); v3 = fmaxf(v3,0.f); }
        if constexpr (RESID) {
          float4 rv = *(const float4*)&resid[(size_t)r*N + col];
          v0 += rv.x; v1 += rv.y; v2 += rv.z; v3 += rv.w;
        }
        float4 o4; o4.x = v0; o4.y = v1; o4.z = v2; o4.w = v3;
        *(float4*)&C[(size_t)r*N + col] = o4;
        if constexpr (NORM) rowsq[i] += v0*v0 + v1*v1 + v2*v2 + v3*v3;
      }
    }
  }
  if constexpr (NORM) {
    if (tid < 64) sNorm[tid] = 0.f;
    __syncthreads();
#pragma unroll
    for (int i = 0; i < 4; ++i) atomicAdd(&sNorm[tr*4+i], rowsq[i]);
    __syncthreads();
    if (tid < 64 && r0 + tid < M) nrm[r0 + tid] = sNorm[tid];
  }
}

// ---------------- LayerNorm (wave-per-row) ----------------
__global__ void __launch_bounds__(256) k_ln(
    const float* __restrict__ x, const float* __restrict__ g, const float* __restrict__ b,
    float* __restrict__ o, int M)
{
  const int lane = threadIdx.x & 63, w = threadIdx.x >> 6;
  int rb = blockIdx.x*32 + w*8;
  for (int it = 0; it < 8; ++it) {
    int r = rb + it;
    if (r >= M) return;
    float a = x[(size_t)r*128 + lane];
    float c = x[(size_t)r*128 + 64 + lane];
    float s = a + c;
    for (int o2 = 32; o2; o2 >>= 1) s += __shfl_xor(s, o2);
    float mu = s * (1.f/128.f);
    float da = a - mu, dc = c - mu;
    float v = da*da + dc*dc;
    for (int o2 = 32; o2; o2 >>= 1) v += __shfl_xor(v, o2);
    float rs = rsqrtf(v*(1.f/128.f) + 1e-5f);
    o[(size_t)r*128 + lane]      = da*rs*g[lane]    + b[lane];
    o[(size_t)r*128 + 64 + lane] = dc*rs*g[lane+64] + b[lane+64];
  }
}

// ---------------- rowmm init ----------------
__global__ void __launch_bounds__(256) k_init_rowmm(unsigned* __restrict__ rowmm)
{
  int i = blockIdx.x*256 + threadIdx.x;   // 2048 entries
  if (i < 2048) rowmm[i] = (i & 1) ? 0xFFFFFFFFu : 0u;  // [even]=max(init 0), [odd]=min(init ~0)
}

// ---------------- sims GEMM: 128 rows x 128 cols per block ----------------
// sims[r][c] = 2*dot(kbc[r], candk[c]) - candn[c]; fused per-row min/max atomics.
// Register tile: 8x8 per thread, split quads (r: tr*4 / 64+tr*4, c: tc*4 / 64+tc*4)
// so LDS reads are broadcast (A) or 2-way (B, free). NO address-taken local arrays.
__global__ void __launch_bounds__(256) k_sims_gemm(
    const float* __restrict__ kbc,    // [128][128] chunk of kb
    const float* __restrict__ candk,  // [NCAND][128]
    const float* __restrict__ candn,  // [NCAND]
    float* __restrict__ sims,         // [128][NCAND]
    unsigned* __restrict__ rowmm)     // [128][2]
{
  __shared__ __align__(16) float sAT[32*128];  // [k][r]
  __shared__ __align__(16) float sBT[32*128];  // [k][c]
  const int tid = threadIdx.x;
  const int c0 = blockIdx.x * 128;
  const int tr = tid >> 4, tc = tid & 15;
  const int ra = tr*4;          // rows ra..ra+3 and ra+64..ra+67
  const int ca = tc*4;          // cols ca..ca+3 and ca+64..ca+67

  float acc[8][8];              // constant-index only -> stays in VGPRs
#pragma unroll
  for (int i = 0; i < 8; ++i)
#pragma unroll
    for (int j = 0; j < 8; ++j) acc[i][j] = 0.f;

  for (int ks = 0; ks < 128; ks += 32) {
    // stage A slice transposed [k][r]
    for (int i = tid; i < 1024; i += 256) {
      int r = i & 127, k4 = i >> 7;          // k4 in 0..7
      float4 a = *(const float4*)&kbc[(size_t)r*128 + ks + k4*4];
      sAT[(k4*4+0)*128 + r] = a.x;
      sAT[(k4*4+1)*128 + r] = a.y;
      sAT[(k4*4+2)*128 + r] = a.z;
      sAT[(k4*4+3)*128 + r] = a.w;
    }
    // stage B slice transposed [k][c] (coalesced global reads)
    for (int i = tid; i < 1024; i += 256) {
      int c = i >> 3, k4 = i & 7;
      int gc = c0 + c;
      float4 bv;
      if (gc < NCAND) bv = *(const float4*)&candk[(size_t)gc*128 + ks + k4*4];
      else { bv.x = bv.y = bv.z = bv.w = 0.f; }
      sBT[(k4*4+0)*128 + c] = bv.x;
      sBT[(k4*4+1)*128 + c] = bv.y;
      sBT[(k4*4+2)*128 + c] = bv.z;
      sBT[(k4*4+3)*128 + c] = bv.w;
    }
    __syncthreads();
#pragma unroll 4
    for (int k = 0; k < 32; ++k) {
      float4 aLo = *(const float4*)&sAT[k*128 + ra];
      float4 aHi = *(const float4*)&sAT[k*128 + ra + 64];
      float4 bLo = *(const float4*)&sBT[k*128 + ca];
      float4 bHi = *(const float4*)&sBT[k*128 + ca + 64];
#define ROWFMA(i, s) \
      acc[i][0] += (s)*bLo.x; acc[i][1] += (s)*bLo.y; acc[i][2] += (s)*bLo.z; acc[i][3] += (s)*bLo.w; \
      acc[i][4] += (s)*bHi.x; acc[i][5] += (s)*bHi.y; acc[i][6] += (s)*bHi.z; acc[i][7] += (s)*bHi.w;
      ROWFMA(0, aLo.x) ROWFMA(1, aLo.y) ROWFMA(2, aLo.z) ROWFMA(3, aLo.w)
      ROWFMA(4, aHi.x) ROWFMA(5, aHi.y) ROWFMA(6, aHi.z) ROWFMA(7, aHi.w)
#undef ROWFMA
    }
    __syncthreads();
  }

  // epilogue: sims = 2*acc - cn; fused per-row minmax.
  const bool vLo = (c0 + ca) < NCAND;       // NCAND%4==0: quad all-or-nothing
  const bool vHi = (c0 + ca + 64) < NCAND;
  float4 cnLo, cnHi;
  cnLo.x = cnLo.y = cnLo.z = cnLo.w = 0.f;
  cnHi.x = cnHi.y = cnHi.z = cnHi.w = 0.f;
  if (vLo) cnLo = *(const float4*)&candn[c0 + ca];
  if (vHi) cnHi = *(const float4*)&candn[c0 + ca + 64];

#pragma unroll
  for (int i = 0; i < 8; ++i) {
    int r = (i < 4) ? (ra + i) : (ra + 64 + i - 4);
    float vmax = -__builtin_inff(), vmin = __builtin_inff();
    if (vLo) {
      float4 o;
      o.x = 2.f*acc[i][0] - cnLo.x;
      o.y = 2.f*acc[i][1] - cnLo.y;
      o.z = 2.f*acc[i][2] - cnLo.z;
      o.w = 2.f*acc[i][3] - cnLo.w;
      *(float4*)&sims[(size_t)r*NCAND + c0 + ca] = o;
      vmax = fmaxf(fmaxf(o.x,o.y), fmaxf(o.z,o.w));
      vmin = fminf(fminf(o.x,o.y), fminf(o.z,o.w));
    }
    if (vHi) {
      float4 o;
      o.x = 2.f*acc[i][4] - cnHi.x;
      o.y = 2.f*acc[i][5] - cnHi.y;
      o.z = 2.f*acc[i][6] - cnHi.z;
      o.w = 2.f*acc[i][7] - cnHi.w;
      *(float4*)&sims[(size_t)r*NCAND + c0 + ca + 64] = o;
      vmax = fmaxf(vmax, fmaxf(fmaxf(o.x,o.y), fmaxf(o.z,o.w)));
      vmin = fminf(vmin, fminf(fminf(o.x,o.y), fminf(o.z,o.w)));
    }
#pragma unroll
    for (int m = 1; m < 16; m <<= 1) {
      vmax = fmaxf(vmax, __shfl_xor(vmax, m));
      vmin = fminf(vmin, __shfl_xor(vmin, m));
    }
    if ((tid & 15) == 0) {
      atomicMax(&rowmm[r*2+0], fenc(vmax));
      atomicMin(&rowmm[r*2+1], fenc(vmin));
    }
  }
}

// ---------------- top-96 select + softmax + gathers (one block per row) ----------------
__global__ void __launch_bounds__(256) k_select(
    const float* __restrict__ sims, const unsigned* __restrict__ rowmm,
    const float* __restrict__ cand_y,
    float* __restrict__ probs, int* __restrict__ tidxg, float* __restrict__ ygath,
    int r0)
{
  __shared__ unsigned hist[2048];
  __shared__ unsigned wsum[256];
  __shared__ float tv[3072];
  __shared__ int   tix[3072];
  __shared__ float selv[96];
  __shared__ int   seli[96];
  __shared__ unsigned scnt[2];
  __shared__ int sb_s; __shared__ int above_s;
  __shared__ float s_lo, s_inv;
  __shared__ float wv[4]; __shared__ int wp[4];
  __shared__ float smax_s, ssum_s;

  const int tid = threadIdx.x;
  const int row = blockIdx.x;
  const float4* S4 = (const float4*)(sims + (size_t)row*NCAND);

  if (tid == 0) {
    float hi = fdec(rowmm[row*2+0]);
    float lo = fdec(rowmm[row*2+1]);
    float rng = hi - lo;
    s_lo = lo;
    s_inv = (rng > 0.f) ? (2048.f / rng) : 0.f;
    scnt[0] = 0; scnt[1] = 0;
  }
  for (int i = tid; i < 2048; i += 256) hist[i] = 0;
  __syncthreads();
  const float lo = s_lo, inv = s_inv;

  // pass 1: histogram
  for (int i = tid; i < NCAND/4; i += 256) {
    float4 v = S4[i];
    int b0 = min(max((int)((v.x-lo)*inv), 0), 2047);
    int b1 = min(max((int)((v.y-lo)*inv), 0), 2047);
    int b2 = min(max((int)((v.z-lo)*inv), 0), 2047);
    int b3 = min(max((int)((v.w-lo)*inv), 0), 2047);
    atomicAdd(&hist[b0], 1u); atomicAdd(&hist[b1], 1u);
    atomicAdd(&hist[b2], 1u); atomicAdd(&hist[b3], 1u);
  }
  __syncthreads();
  { unsigned s = 0;
#pragma unroll
    for (int j = 0; j < 8; ++j) s += hist[tid*8 + j];
    wsum[tid] = s; }
  __syncthreads();
  if (tid == 0) {
    unsigned cum = 0; int g = 255;
    while (cum + wsum[g] < 96u) { cum += wsum[g]; --g; }
    int b = g*8 + 7;
    while (cum + hist[b] < 96u) { cum += hist[b]; --b; }
    sb_s = b; above_s = (int)cum;
  }
  __syncthreads();
  const int sb = sb_s, above = above_s;

  // pass 2: emission
  for (int i = tid; i < NCAND/4; i += 256) {
    float4 v = S4[i];
    float xs[4] = {v.x, v.y, v.z, v.w};
#pragma unroll
    for (int j = 0; j < 4; ++j) {
      float x = xs[j];
      int b = min(max((int)((x-lo)*inv), 0), 2047);
      if (b > sb) {
        unsigned p = atomicAdd(&scnt[0], 1u);
        selv[p] = x; seli[p] = i*4 + j;
      } else if (b == sb) {
        unsigned p = atomicAdd(&scnt[1], 1u);
        if (p < 3072u) { tv[p] = x; tix[p] = i*4 + j; }
      }
    }
  }
  __syncthreads();
  const int need = 96 - above;
  const int tcnt = min((int)scnt[1], 3072);
  for (int rd = 0; rd < need; ++rd) {
    float best = -__builtin_inff(); int bp = -1;
    for (int t = tid; t < tcnt; t += 256) {
      float v = tv[t];
      if (v > best) { best = v; bp = t; }
    }
    for (int o = 32; o; o >>= 1) {
      float ob = __shfl_xor(best, o); int obp = __shfl_xor(bp, o);
      if (ob > best) { best = ob; bp = obp; }
    }
    if ((tid & 63) == 0) { wv[tid>>6] = best; wp[tid>>6] = bp; }
    __syncthreads();
    if (tid == 0) {
      float bb = wv[0]; int pp = wp[0];
      for (int w2 = 1; w2 < 4; ++w2) if (wv[w2] > bb) { bb = wv[w2]; pp = wp[w2]; }
      selv[above + rd] = bb; seli[above + rd] = tix[pp]; tv[pp] = -__builtin_inff();
    }
    __syncthreads();
  }

  // softmax + gather
  if (tid == 0) {
    float m = selv[0];
    for (int i = 1; i < 96; ++i) m = fmaxf(m, selv[i]);
    smax_s = m;
  }
  __syncthreads();
  if (tid < 96) selv[tid] = expf(selv[tid] - smax_s);
  __syncthreads();
  if (tid == 0) {
    float s = 0.f;
    for (int i = 0; i < 96; ++i) s += selv[i];
    ssum_s = s;
  }
  __syncthreads();
  if (tid < 96) {
    int gr = r0 + row;
    int gi = seli[tid];
    probs[(size_t)gr*96 + tid] = selv[tid]/ssum_s;
    tidxg[(size_t)gr*96 + tid] = gi;
    ygath[(size_t)gr*96 + tid] = cand_y[gi];
  }
}

// ---------------- t-net gather: diff = k_b - cand_k[idx] ----------------
__global__ void __launch_bounds__(256) k_gather_diff(
    const float* __restrict__ kb, const float* __restrict__ candk,
    const int* __restrict__ tidxg, float* __restrict__ diff, int p0)
{
  int f = blockIdx.x*256 + threadIdx.x;
  int pl = f >> 7, d = f & 127;
  int gp = p0 + pl;
  int bb = gp / 96;
  int idx = tidxg[gp];
  diff[f] = kb[(size_t)bb*128 + d] - candk[(size_t)idx*128 + d];
}

// ---------------- context accumulation + residual add ----------------
__global__ void __launch_bounds__(128) k_ctx(
    const float* __restrict__ probs, const float* __restrict__ ygath,
    const float* __restrict__ t2, const float* __restrict__ x2b,
    const float* __restrict__ w_le, const float* __restrict__ b_le,
    float* __restrict__ xfinal, int b0)
{
  int bb = b0 + blockIdx.x;
  int d = threadIdx.x;
  float wle = w_le[d], ble = b_le[d];
  float acc = 0.f;
  int base = (bb - b0)*96;
  for (int c = 0; c < 96; ++c) {
    float p = probs[(size_t)bb*96 + c];
    float y = ygath[(size_t)bb*96 + c];
    acc += p*(y*wle + ble + t2[(size_t)(base + c)*128 + d]);
  }
  xfinal[(size_t)bb*128 + d] = x2b[(size_t)bb*128 + d] + acc;
}

// ---------------- head ----------------
__global__ void __launch_bounds__(256) k_head(
    const float* __restrict__ x, const float* __restrict__ g, const float* __restrict__ b,
    const float* __restrict__ Wh, const float* __restrict__ bh,
    float* __restrict__ out, int M)
{
  const int lane = threadIdx.x & 63, w = threadIdx.x >> 6;
  int rb = blockIdx.x*32 + w*8;
  for (int it = 0; it < 8; ++it) {
    int r = rb + it;
    if (r >= M) return;
    float a = x[(size_t)r*128 + lane];
    float c = x[(size_t)r*128 + 64 + lane];
    float s = a + c;
    for (int o = 32; o; o >>= 1) s += __shfl_xor(s, o);
    float mu = s*(1.f/128.f);
    float da = a - mu, dc = c - mu;
    float v = da*da + dc*dc;
    for (int o = 32; o; o >>= 1) v += __shfl_xor(v, o);
    float rs = rsqrtf(v*(1.f/128.f) + 1e-5f);
    float l0 = fmaxf(da*rs*g[lane]    + b[lane],    0.f);
    float l1 = fmaxf(dc*rs*g[lane+64] + b[lane+64], 0.f);
    float p0 = l0*Wh[lane]     + l1*Wh[64+lane];
    float p1 = l0*Wh[128+lane] + l1*Wh[192+lane];
    for (int o = 32; o; o >>= 1) { p0 += __shfl_xor(p0, o); p1 += __shfl_xor(p1, o); }
    if (lane == 0) { out[r*2 + 0] = p0 + bh[0]; out[r*2 + 1] = p1 + bh[1]; }
  }
}

// ---------------- launcher ----------------
extern "C" void kernel_launch(void* const* d_in, const int* in_sizes, int n_in,
                              void* d_out, int out_size, void* d_ws, size_t ws_size,
                              hipStream_t stream) {
  const float* x_num   = (const float*)d_in[0];
  const float* cand_x  = (const float*)d_in[1];
  const float* cand_y  = (const float*)d_in[2];
  const float* W_in    = (const float*)d_in[3];
  const float* b_in    = (const float*)d_in[4];
  const float* enc_W1  = (const float*)d_in[5];
  const float* enc_b1  = (const float*)d_in[6];
  const float* enc_W2  = (const float*)d_in[7];
  const float* enc_b2  = (const float*)d_in[8];
  const float* mix_g   = (const float*)d_in[9];
  const float* mix_b   = (const float*)d_in[10];
  const float* W_k     = (const float*)d_in[11];
  const float* b_k     = (const float*)d_in[12];
  const float* w_le    = (const float*)d_in[13];
  const float* b_le    = (const float*)d_in[14];
  const float* W_t1    = (const float*)d_in[15];
  const float* b_t1    = (const float*)d_in[16];
  const float* W_t2    = (const float*)d_in[17];
  const float* pred_g  = (const float*)d_in[18];
  const float* pred_b  = (const float*)d_in[19];
  const float* pred_W1 = (const float*)d_in[20];
  const float* pred_b1 = (const float*)d_in[21];
  const float* pred_W2 = (const float*)d_in[22];
  const float* pred_b2 = (const float*)d_in[23];
  const float* head_g  = (const float*)d_in[24];
  const float* head_b  = (const float*)d_in[25];
  const float* W_head  = (const float*)d_in[26];
  const float* b_head  = (const float*)d_in[27];

  float* ws  = (float*)d_ws;
  float* out = (float*)d_out;

  float*    wt     = ws;
  float*    candk  = ws + OFF_CANDK;
  float*    candn  = ws + OFF_CANDN;
  float*    kb     = ws + OFF_KB;
  unsigned* rowmm  = (unsigned*)(ws + OFF_ROWMM);
  float*    xb     = ws + OFF_XB;
  float*    x2b    = ws + OFF_X2B;
  float*    lnb    = ws + OFF_LNB;
  float*    hb     = ws + OFF_HB;
  float*    xpred  = ws + OFF_XPRED;
  float*    xfin   = ws + OFF_XFIN;
  float*    probs  = ws + OFF_PROBS;
  int*      tidxg  = (int*)(ws + OFF_TIDX);
  float*    ygath  = ws + OFF_YG;
  float*    sx     = ws + OFF_SX;
  float*    sx2    = ws + OFF_SX2;
  float*    sh     = ws + OFF_SH;
  float*    sln    = ws + OFF_SLN;
  float*    simsbuf = ws + OFF_SX;   // 128*100000 floats, overlaps dead enc scratch

  // 1) weight transposes
  k_transpose<<<256, 256, 0, stream>>>(W_in, enc_W1, enc_W2, W_k, W_t1, W_t2, pred_W1, pred_W2, wt);

  // 2) batch encoder
  k_gemm<128,false,false,false><<<16, 256, 0, stream>>>(x_num, wt+WT_IN, b_in,   nullptr, xb,  nullptr, BATCH, 64);
  k_gemm<256,true ,false,false><<<16, 256, 0, stream>>>(xb,    wt+WT_E1, enc_b1, nullptr, hb,  nullptr, BATCH, 128);
  k_gemm<128,false,true ,false><<<16, 256, 0, stream>>>(hb,    wt+WT_E2, enc_b2, xb,      x2b, nullptr, BATCH, 256);
  k_ln<<<(BATCH+31)/32, 256, 0, stream>>>(x2b, mix_g, mix_b, lnb, BATCH);
  k_gemm<128,false,false,false><<<16, 256, 0, stream>>>(lnb,   wt+WT_K,  b_k,    nullptr, kb,  nullptr, BATCH, 128);

  // 3) candidate encoder, 4 chunks of 25000
  for (int ch = 0; ch < 4; ++ch) {
    const float* a0 = cand_x + (size_t)ch*ECH*64;
    float* ck = candk + (size_t)ch*ECH*128;
    float* cn = candn + (size_t)ch*ECH;
    int grid = (ECH + 63)/64;
    k_gemm<128,false,false,false><<<grid, 256, 0, stream>>>(a0,  wt+WT_IN, b_in,   nullptr, sx,  nullptr, ECH, 64);
    k_gemm<256,true ,false,false><<<grid, 256, 0, stream>>>(sx,  wt+WT_E1, enc_b1, nullptr, sh,  nullptr, ECH, 128);
    k_gemm<128,false,true ,false><<<grid, 256, 0, stream>>>(sh,  wt+WT_E2, enc_b2, sx,      sx2, nullptr, ECH, 256);
    k_ln<<<(ECH+31)/32, 256, 0, stream>>>(sx2, mix_g, mix_b, sln, ECH);
    k_gemm<128,false,false,true ><<<grid, 256, 0, stream>>>(sln, wt+WT_K,  b_k,    nullptr, ck,  cn,      ECH, 128);
  }

  // 4) sims + exact top-96, 8 row chunks of 128
  k_init_rowmm<<<8, 256, 0, stream>>>(rowmm);
  for (int ch = 0; ch < 8; ++ch) {
    k_sims_gemm<<<(NCAND+127)/128, 256, 0, stream>>>(
        kb + (size_t)ch*RCH*128, candk, candn, simsbuf, rowmm + ch*RCH*2);
    k_select<<<RCH, 256, 0, stream>>>(
        simsbuf, rowmm + ch*RCH*2, cand_y, probs, tidxg, ygath, ch*RCH);
  }

  // 5) t-net, 4 chunks of 256 batch rows
  for (int tc = 0; tc < 4; ++tc) {
    int p0 = tc*TP, b0 = tc*TROWS;
    k_gather_diff<<<(TP*128)/256, 256, 0, stream>>>(kb, candk, tidxg, sln, p0);
    k_gemm<256,true ,false,false><<<TP/64, 256, 0, stream>>>(sln, wt+WT_T1, b_t1, nullptr, sh, nullptr, TP, 128);
    k_gemm<128,false,false,false><<<TP/64, 256, 0, stream>>>(sh,  wt+WT_T2, nullptr, nullptr, sx, nullptr, TP, 256);
    k_ctx<<<TROWS, 128, 0, stream>>>(probs, ygath, sx, x2b, w_le, b_le, xfin, b0);
  }

  // 6) predictor block + head
  k_ln<<<(BATCH+31)/32, 256, 0, stream>>>(xfin, pred_g, pred_b, lnb, BATCH);
  k_gemm<256,true ,false,false><<<16, 256, 0, stream>>>(lnb, wt+WT_P1, pred_b1, nullptr, hb,    nullptr, BATCH, 128);
  k_gemm<128,false,true ,false><<<16, 256, 0, stream>>>(hb,  wt+WT_P2, pred_b2, xfin,    xpred, nullptr, BATCH, 256);
  k_head<<<(BATCH+31)/32, 256, 0, stream>>>(xpred, head_g, head_b, W_head, b_head, out, BATCH);
}